// Round 8
// baseline (206.969 us; speedup 1.0000x reference)
//
#include <hip/hip_runtime.h>
#include <stdint.h>

// ---------------- problem constants ----------------
#define BB 4
#define RR 4
#define NN 4096
#define MM 64
#define KK 3
#define KNN 12288           // KK*NN
#define BRR 16              // BB*RR
#define FF 512

typedef short bf16x8 __attribute__((ext_vector_type(8)));
typedef float f32x4 __attribute__((ext_vector_type(4)));

__device__ __forceinline__ float bf2f(unsigned int u) {
  union { unsigned int i; float f; } v; v.i = u << 16; return v.f;
}
__device__ __forceinline__ unsigned short f2bf(float f) {
  union { float f; unsigned int i; } v; v.f = f;
  unsigned int x = v.i;
  return (unsigned short)((x + 0x7fffu + ((x >> 16) & 1u)) >> 16);
}
// packed RNE f32x2 -> bf16x2 (T12 recipe; no builtin on gfx950)
__device__ __forceinline__ unsigned int cvtpk(float a, float b) {
  unsigned int r;
  asm("v_cvt_pk_bf16_f32 %0, %1, %2" : "=v"(r) : "v"(a), "v"(b));
  return r;
}
// dtype-adaptive load: isbf=1 -> buffer is bf16 ushorts; else fp32 floats
__device__ __forceinline__ float ldf(const void* p, long i, int isbf) {
  if (isbf) return bf2f(((const unsigned short*)p)[i]);
  return ((const float*)p)[i];
}
// LDS bank-conflict swizzles (XOR short-offset bits 3..4 with col bits 3..4).
__device__ __forceinline__ int hsw(int col, int so) { return col * 72  + (so ^ (col & 24)); }
__device__ __forceinline__ int csw(int col, int so) { return col * 168 + (so ^ (col & 24)); } // so < 160

struct WPtrs { const void* p[16]; };
// 0..6: fpW1,fpW2,fpW3,gpW0,gpW1,gpW2,gpW3 (-> Wb bf16)
// 7..15: fpW0,fpb0,fpb1,fpb2,fpb3,gpb0,gpb1,gpb2,gpb3 (-> Fb f32)
// Fb float layout: fW0@0(128) fb0@128(64) fb1@192(64) fb2@256(128) fb3@384(128)
//                  gpb0@512(256) gpb1@768(256) gpb2@1024(512) gpb3@1536(512)

// ---------------- K0: merged dtype-probe + weight-cvt(x8 vec) + assign ----------------
// blocks [0,298): canonicalize weights, 8 elems/thread (Wb bf16, fW3p K160, Fb f32)
// blocks [298,362): top-3 assignment + cluster sums + per-block histogram
__global__ __launch_bounds__(256) void k_front(
    const void* __restrict__ x, const void* __restrict__ node, WPtrs wp,
    int* __restrict__ flag, unsigned short* __restrict__ Wb,
    unsigned short* __restrict__ fW3p, float* __restrict__ Fb,
    int* __restrict__ idx, float* __restrict__ csum, int* __restrict__ blkcnt) {
  __shared__ int bad;
  __shared__ float nd[2][64];
  __shared__ float cs[192];   // [m][{sx,sy,cnt}]
  int tid = threadIdx.x;
  if (tid == 0) bad = 0;
  __syncthreads();
  {
    const unsigned short* xs = (const unsigned short*)x;
    int cnt = 0;
    for (int i = tid; i < 1024; i += 256) {
      unsigned short u = xs[i * 2];
      int e = (u >> 7) & 0xFF;
      if (e >= 0x90 || (e > 0 && e <= 0x50)) ++cnt;
    }
    atomicAdd(&bad, cnt);
  }
  __syncthreads();
  int isbf = (bad < 100) ? 1 : 0;
  if (blockIdx.x == 0 && tid == 0) flag[0] = isbf;

  if (blockIdx.x < 298) {
    const int e0=4096, e1=12288, e2=28928, e3=62208, e4=127744, e5=258816, e6=587520;
    int t8 = blockIdx.x * 256 + tid;
    if (t8 < 73440) {
      // ---- Wb: 8 contiguous elems; all segment boundaries are /8 ----
      int base = t8 * 8;
      int s, segb;
      if      (base < e0) { s=0; segb=0;  }
      else if (base < e1) { s=1; segb=e0; }
      else if (base < e2) { s=2; segb=e1; }
      else if (base < e3) { s=3; segb=e2; }
      else if (base < e4) { s=4; segb=e3; }
      else if (base < e5) { s=5; segb=e4; }
      else                { s=6; segb=e5; }
      int local = base - segb;
      union { bf16x8 v; unsigned int u[4]; } ov;
      if (isbf) {
        ov.v = *(const bf16x8*)((const unsigned short*)wp.p[s] + local);
      } else {
        const float4* fp = (const float4*)((const float*)wp.p[s] + local);
        float4 f0 = fp[0], f1 = fp[1];
        ov.u[0] = cvtpk(f0.x, f0.y); ov.u[1] = cvtpk(f0.z, f0.w);
        ov.u[2] = cvtpk(f1.x, f1.y); ov.u[3] = cvtpk(f1.z, f1.w);
      }
      *(bf16x8*)(Wb + base) = ov.v;
    } else if (t8 < 76000) {
      // ---- fW3 zero-padded to 128 x 160 (20480 elems, 8/thread) ----
      int v = t8 - 73440;
      int base = v * 8;
      int o = v / 20, c = (v - o * 20) * 8;    // 160 = 20*8
      union { bf16x8 vv; unsigned short s8[8]; } ov;
#pragma unroll
      for (int j = 0; j < 8; ++j) {
        int cc = c + j;
        unsigned short u = 0;
        if (cc < 130) {
          long si = (long)o * 130 + cc;
          if (isbf) u = ((const unsigned short*)wp.p[2])[si];
          else      u = f2bf(((const float*)wp.p[2])[si]);
        }
        ov.s8[j] = u;
      }
      *(bf16x8*)(fW3p + base) = ov.vv;
    } else if (t8 < 76256) {
      // ---- f32 table: fW0 + all biases (2048 floats, 8/thread; bounds /8) ----
      int l = (t8 - 76000) * 8;
      const void* src; int off;
      if      (l < 128)  { src = wp.p[7];  off = 0;    }
      else if (l < 192)  { src = wp.p[8];  off = 128;  }
      else if (l < 256)  { src = wp.p[9];  off = 192;  }
      else if (l < 384)  { src = wp.p[10]; off = 256;  }
      else if (l < 512)  { src = wp.p[11]; off = 384;  }
      else if (l < 768)  { src = wp.p[12]; off = 512;  }
      else if (l < 1024) { src = wp.p[13]; off = 768;  }
      else if (l < 1536) { src = wp.p[14]; off = 1024; }
      else               { src = wp.p[15]; off = 1536; }
#pragma unroll
      for (int j = 0; j < 8; ++j) Fb[l + j] = ldf(src, l + j - off, isbf);
    }
    return;
  }
  // ---- assign ----
  int bi = blockIdx.x - 298;         // b*16 + chunk
  int b = bi >> 4;
  int n = ((bi & 15) << 8) + tid;
  if (tid < 128) nd[tid >> 6][tid & 63] = ldf(node, b * 128 + tid, isbf);
  if (tid < 192) cs[tid] = 0.f;
  __syncthreads();
  float x0 = ldf(x, b * 8192 + n, isbf);
  float x1 = ldf(x, b * 8192 + 4096 + n, isbf);
  float d0 = 1e30f, d1 = 1e30f, d2 = 1e30f;
  int m0 = 0, m1 = 0, m2 = 0;
#pragma unroll 8
  for (int m = 0; m < 64; ++m) {
    float dx = x0 - nd[0][m];
    float dy = x1 - nd[1][m];
    float d = __fmul_rn(dx, dx) + __fmul_rn(dy, dy);   // no contraction: match ref
    if (d < d0)      { d2=d1; m2=m1; d1=d0; m1=m0; d0=d; m0=m; }
    else if (d < d1) { d2=d1; m2=m1; d1=d;  m1=m; }
    else if (d < d2) { d2=d;  m2=m; }
  }
  long base = ((long)b * NN + n) * 3;
  idx[base] = m0; idx[base + 1] = m1; idx[base + 2] = m2;
  atomicAdd(&cs[m0*3+0], x0); atomicAdd(&cs[m0*3+1], x1); atomicAdd(&cs[m0*3+2], 1.f);
  atomicAdd(&cs[m1*3+0], x0); atomicAdd(&cs[m1*3+1], x1); atomicAdd(&cs[m1*3+2], 1.f);
  atomicAdd(&cs[m2*3+0], x0); atomicAdd(&cs[m2*3+1], x1); atomicAdd(&cs[m2*3+2], 1.f);
  __syncthreads();
  if (tid < 192) atomicAdd(&csum[b * 192 + tid], cs[tid]);
  if (tid < 64) blkcnt[bi * 64 + tid] = (int)cs[tid*3 + 2];
}

// ---------------- K1: merged means + counting-sort scatter ----------------
__global__ __launch_bounds__(256) void k_scatter2(
    const float* __restrict__ csum, const int* __restrict__ blkcnt,
    const int* __restrict__ idx, int* __restrict__ sorted,
    float* __restrict__ noderot, int* __restrict__ rowflag) {
  __shared__ int scnt[64];
  __shared__ int soff[64];
  __shared__ int lc[64];
  int tid = threadIdx.x;
  int blk = blockIdx.x;              // b*16 + chunk (matches k_front assign)
  int b = blk >> 4, chunk = blk & 15;
  if (tid < 64) scnt[tid] = (int)csum[b*192 + tid*3 + 2];
  __syncthreads();
  if (tid < 64) {
    int m = tid, acc = 0;
    for (int mm = 0; mm < m; ++mm) acc += scnt[mm];          // counts are exact floats
    for (int c = 0; c < chunk; ++c) acc += blkcnt[(b*16 + c)*64 + m];
    soff[m] = acc;
    lc[m] = 0;
    if (chunk == 0) {
      float s0 = csum[b*192 + m*3], s1 = csum[b*192 + m*3 + 1], cc = csum[b*192 + m*3 + 2];
      float mx = s0 / (cc + 1e-5f);
      float my = s1 / (cc + 1e-5f);
      rowflag[b*64 + m] = (cc > 0.f) ? 1 : 0;
      for (int r = 0; r < 4; ++r) {
        float th = 1.5707964f * (float)r;
        float cr = cosf(th), sr = sinf(th);
        noderot[((b*4 + r)*2 + 0)*64 + m] = cr*mx - sr*my;
        noderot[((b*4 + r)*2 + 1)*64 + m] = sr*mx + cr*my;
      }
    }
  }
  __syncthreads();
  int n = ((blk & 15) << 8) + tid;
#pragma unroll
  for (int kk = 0; kk < 3; ++kk) {
    int m = idx[((long)b * NN + n) * 3 + kk];
    int pos = atomicAdd(&lc[m], 1);                 // LDS atomic, order irrelevant
    sorted[b * KNN + soff[m] + pos] = (m << 12) | n;
  }
}

// ---------------- K5: fused fp block (r4-exact) + gp-weight L2 warm ----------------
__global__ __launch_bounds__(256) void k_fused(
    const void* __restrict__ x, const int* __restrict__ sorted,
    const int* __restrict__ idx, const float* __restrict__ noderot,
    const int* __restrict__ flag, const unsigned short* __restrict__ Wb,
    const unsigned short* __restrict__ fW3p, const float* __restrict__ Fb,
    unsigned int* __restrict__ pooled, float* __restrict__ feat0) {
  __shared__ unsigned short Cs[64 * 168];   // [col][0..1]=xdec,[2..129]=h2,[130..159]=0; later [0..127]=feat
  __shared__ unsigned short Hs[64 * 72];    // h1
  __shared__ int mcol[64];                  // m | (is_col0 << 8)
  const unsigned short* fW1 = Wb;           // 64x64
  const unsigned short* fW2 = Wb + 4096;    // 128x64
  int isbf = flag[0];
  int tid = threadIdx.x, lane = tid & 63, wv = tid >> 6;
  int quad = lane >> 4, lr = lane & 15;
  int br = blockIdx.y, b = br >> 2, r = br & 3;
  int o1 = wv * 16;
  // ---- L2 warm: replicate gp weights [28928,587520) into this XCD's L2.
  // slice by blockIdx.x (192 slices x 2912 shorts); each slice hit by 16
  // y-blocks spread across XCDs. XOR keeps loads live (rule #17).
  {
    unsigned int wacc = 0;
#pragma unroll
    for (int i = 0; i < 2; ++i) {
      int off = 28928 + blockIdx.x * 2912 + i * 2048 + tid * 8;
      if (off < 587520) {
        const unsigned int* p = (const unsigned int*)(Wb + off);
        wacc ^= p[0] ^ p[1] ^ p[2] ^ p[3];
      }
    }
    asm volatile("" :: "v"(wacc));
  }
  if (tid < 64) {
    int e = sorted[b * KNN + blockIdx.x * 64 + tid];
    int m = e >> 12, n = e & 4095;
    int isz = (n == 0 && m == idx[(long)b * NN * 3]) ? 256 : 0;
    mcol[tid] = m | isz;
    float x0 = ldf(x, b*8192 + n, isbf), x1 = ldf(x, b*8192 + 4096 + n, isbf);
    float th = 1.5707964f * (float)r;
    float cr = cosf(th), sr = sinf(th);
    float xd0 = (cr*x0 - sr*x1) - noderot[(br*2 + 0)*64 + m];
    float xd1 = (sr*x0 + cr*x1) - noderot[(br*2 + 1)*64 + m];
    *(unsigned int*)&Cs[csw(tid, 0)] = cvtpk(xd0, xd1);
  }
  // zero logical channels 130..159 (once per block; never overwritten)
  for (int z = tid; z < 960; z += 256) {
    int col = z / 15, l = 130 + (z - col * 15) * 2;
    *(unsigned int*)&Cs[csw(col, l)] = 0u;
  }
  __syncthreads();
  // ----- layer0 (2 -> 64), VALU, weights/bias from f32 table -----
  {
    int col = tid & 63, og = (tid >> 6) << 4;
    unsigned int xu = *(unsigned int*)&Cs[csw(col, 0)];
    float fx0 = bf2f(xu & 0xffff), fx1 = bf2f(xu >> 16);
    const float2* w2 = (const float2*)Fb;
    float hv[16];
#pragma unroll
    for (int j = 0; j < 16; ++j) {
      int o = og + j;
      float2 w = w2[o];
      float h = Fb[128 + o] + w.x * fx0 + w.y * fx1;
      hv[j] = fmaxf(h, 0.f);
    }
    union { bf16x8 v; unsigned int u[4]; } o8[2];
#pragma unroll
    for (int j = 0; j < 16; j += 2) o8[j >> 3].u[(j & 7) >> 1] = cvtpk(hv[j], hv[j+1]);
    *(bf16x8*)&Hs[hsw(col, og)]     = o8[0].v;
    *(bf16x8*)&Hs[hsw(col, og + 8)] = o8[1].v;
  }
  __syncthreads();
  // ----- layer1 (64 -> 64), MFMA -----
  {
    f32x4 acc[4];
#pragma unroll
    for (int nt = 0; nt < 4; ++nt)
      acc[nt] = (f32x4){Fb[192 + o1 + quad*4], Fb[192 + o1 + quad*4 + 1],
                        Fb[192 + o1 + quad*4 + 2], Fb[192 + o1 + quad*4 + 3]};
#pragma unroll
    for (int ks2 = 0; ks2 < 2; ++ks2) {
      bf16x8 a = *(const bf16x8*)(fW1 + (o1 + lr)*64 + ks2*32 + quad*8);
#pragma unroll
      for (int nt = 0; nt < 4; ++nt) {
        bf16x8 bf = *(bf16x8*)&Hs[hsw(nt*16 + lr, ks2*32 + quad*8)];
        acc[nt] = __builtin_amdgcn_mfma_f32_16x16x32_bf16(a, bf, acc[nt], 0, 0, 0);
      }
    }
    __syncthreads();  // everyone done READING Hs
#pragma unroll
    for (int nt = 0; nt < 4; ++nt) {
      int col = nt*16 + lr;
      unsigned int lo = cvtpk(fmaxf(acc[nt][0], 0.f), fmaxf(acc[nt][1], 0.f));
      unsigned int hi = cvtpk(fmaxf(acc[nt][2], 0.f), fmaxf(acc[nt][3], 0.f));
      *(unsigned long long*)&Hs[hsw(col, o1 + quad*4)] =
          (unsigned long long)lo | ((unsigned long long)hi << 32);
    }
  }
  __syncthreads();
  // ----- layer2 (64 -> 128), MFMA, output into Cs logical [2..129] -----
#pragma unroll
  for (int p2 = 0; p2 < 2; ++p2) {
    int o0 = p2*64 + o1;
    f32x4 acc[4];
#pragma unroll
    for (int nt = 0; nt < 4; ++nt)
      acc[nt] = (f32x4){Fb[256 + o0 + quad*4], Fb[256 + o0 + quad*4 + 1],
                        Fb[256 + o0 + quad*4 + 2], Fb[256 + o0 + quad*4 + 3]};
#pragma unroll
    for (int ks2 = 0; ks2 < 2; ++ks2) {
      bf16x8 a = *(const bf16x8*)(fW2 + (o0 + lr)*64 + ks2*32 + quad*8);
#pragma unroll
      for (int nt = 0; nt < 4; ++nt) {
        bf16x8 bf = *(bf16x8*)&Hs[hsw(nt*16 + lr, ks2*32 + quad*8)];
        acc[nt] = __builtin_amdgcn_mfma_f32_16x16x32_bf16(a, bf, acc[nt], 0, 0, 0);
      }
    }
#pragma unroll
    for (int nt = 0; nt < 4; ++nt) {
      int col = nt*16 + lr;
      int o = o0 + quad*4;
      unsigned int w0 = cvtpk(fmaxf(acc[nt][0], 0.f), fmaxf(acc[nt][1], 0.f));
      unsigned int w1 = cvtpk(fmaxf(acc[nt][2], 0.f), fmaxf(acc[nt][3], 0.f));
      *(unsigned int*)&Cs[csw(col, 2 + o)] = w0;
      *(unsigned int*)&Cs[csw(col, 4 + o)] = w1;
    }
  }
  __syncthreads();
  // ----- layer3 (K padded to 160): 5 clean MFMA steps, no scalar tail -----
  f32x4 acc3[2][4];
#pragma unroll
  for (int p3 = 0; p3 < 2; ++p3) {
    int o0 = p3*64 + o1;
#pragma unroll
    for (int nt = 0; nt < 4; ++nt)
      acc3[p3][nt] = (f32x4){Fb[384 + o0 + quad*4], Fb[384 + o0 + quad*4 + 1],
                             Fb[384 + o0 + quad*4 + 2], Fb[384 + o0 + quad*4 + 3]};
#pragma unroll
    for (int ks5 = 0; ks5 < 5; ++ks5) {
      bf16x8 a = *(const bf16x8*)(fW3p + (o0 + lr)*160 + ks5*32 + quad*8);
#pragma unroll
      for (int nt = 0; nt < 4; ++nt) {
        bf16x8 bf = *(bf16x8*)&Cs[csw(nt*16 + lr, ks5*32 + quad*8)];
        acc3[p3][nt] = __builtin_amdgcn_mfma_f32_16x16x32_bf16(a, bf, acc3[p3][nt], 0, 0, 0);
      }
    }
  }
  __syncthreads();   // ALL Cs reads complete before feat overwrite
#pragma unroll
  for (int p3 = 0; p3 < 2; ++p3) {
    int o0 = p3*64 + o1;
#pragma unroll
    for (int nt = 0; nt < 4; ++nt) {
      int col = nt*16 + lr;
      unsigned int lo = cvtpk(fmaxf(acc3[p3][nt][0], 0.f), fmaxf(acc3[p3][nt][1], 0.f));
      unsigned int hi = cvtpk(fmaxf(acc3[p3][nt][2], 0.f), fmaxf(acc3[p3][nt][3], 0.f));
      *(unsigned long long*)&Cs[csw(col, o0 + quad*4)] =
          (unsigned long long)lo | ((unsigned long long)hi << 32);
    }
  }
  __syncthreads();
  // ----- run-scan segment max: packed u32, integer max (bf16>=0 => u16 order) ---
  {
    int opair = tid & 63, h = tid >> 6;      // wave-uniform h: 4 waves x 16 cols
    int o0 = opair * 2;
    int c0 = h * 16;
    int curm = mcol[c0] & 255;
    unsigned int vlo = 0u, vhi = 0u;
    for (int c = c0; c < c0 + 16; ++c) {
      int mc = mcol[c];
      int mm = mc & 255;
      unsigned int u = *(unsigned int*)&Cs[csw(c, o0)];
      if (mm != curm) {
        atomicMax(&pooled[(((long)br*64 + curm) << 7) + o0],     vlo);
        atomicMax(&pooled[(((long)br*64 + curm) << 7) + o0 + 1], vhi);
        curm = mm; vlo = vhi = 0u;
      }
      vlo = max(vlo, u << 16);
      vhi = max(vhi, u & 0xffff0000u);
      if (mc & 256) {
        feat0[br*128 + o0]     = __uint_as_float(u << 16);
        feat0[br*128 + o0 + 1] = __uint_as_float(u & 0xffff0000u);
      }
    }
    atomicMax(&pooled[(((long)br*64 + curm) << 7) + o0],     vlo);
    atomicMax(&pooled[(((long)br*64 + curm) << 7) + o0 + 1], vhi);
  }
}

// ---------------- gp layer helper: chunked loads (4 ks-steps batched) ----------
// Per chunk: issue 4 LDS reads + 4*OT global weight loads back-to-back into a
// statically-indexed staging array, then 4*OT MFMAs. ~8 in-flight global loads
// per wave (vs ~2 when the compiler serialized at VGPR=40).
template<int OT, int KW, int KMAIN, bool REM2, int DSTR, int DOFF, int EPI>
__device__ __forceinline__ void gp_layer(
    const unsigned short* __restrict__ W, const float* __restrict__ bias,
    const unsigned short* Bs, int bstr, unsigned short* Ds,
    int wv, int quad, int lr, int b, unsigned int* __restrict__ outmax) {
  f32x4 acc[OT];
#pragma unroll
  for (int ot = 0; ot < OT; ++ot) {
    int o0 = (wv * OT + ot) * 16;
    acc[ot] = (f32x4){bias[o0 + quad*4], bias[o0 + quad*4 + 1],
                      bias[o0 + quad*4 + 2], bias[o0 + quad*4 + 3]};
  }
  const unsigned short* brow = Bs + lr * bstr;
  constexpr int NS = KMAIN / 32;      // 4, 8, or 20 -- all divisible by 4
#pragma unroll 1
  for (int c = 0; c < NS; c += 4) {
    bf16x8 bfv[4];
    bf16x8 av[4][OT];
#pragma unroll
    for (int j = 0; j < 4; ++j) {
      int ks = (c + j) * 32;
      bfv[j] = *(const bf16x8*)(brow + ks + quad*8);
#pragma unroll
      for (int ot = 0; ot < OT; ++ot) {
        const unsigned short* arow = W + (long)((wv * OT + ot) * 16 + lr) * KW;
        if constexpr ((KW % 8) == 0) {
          av[j][ot] = *(const bf16x8*)(arow + ks + quad*8);
        } else {
          union { bf16x8 v; unsigned int u[4]; } au;
          const unsigned int* ap = (const unsigned int*)(arow + ks + quad*8);  // 4B aligned
          au.u[0] = ap[0]; au.u[1] = ap[1]; au.u[2] = ap[2]; au.u[3] = ap[3];
          av[j][ot] = au.v;
        }
      }
    }
#pragma unroll
    for (int j = 0; j < 4; ++j)
#pragma unroll
      for (int ot = 0; ot < OT; ++ot)
        acc[ot] = __builtin_amdgcn_mfma_f32_16x16x32_bf16(av[j][ot], bfv[j], acc[ot], 0, 0, 0);
  }
  if constexpr (REM2) {
    unsigned int bu = *(const unsigned int*)(brow + KMAIN);
    float b0 = bf2f(bu & 0xffff), b1 = bf2f(bu >> 16);
#pragma unroll
    for (int ot = 0; ot < OT; ++ot) {
#pragma unroll
      for (int rr = 0; rr < 4; ++rr) {
        int o = (wv * OT + ot) * 16 + quad*4 + rr;
        unsigned int wu = *(const unsigned int*)(W + (long)o * KW + KMAIN);
        acc[ot][rr] += bf2f(wu & 0xffff) * b0 + bf2f(wu >> 16) * b1;
      }
    }
  }
#pragma unroll
  for (int ot = 0; ot < OT; ++ot) {
    int o0 = (wv * OT + ot) * 16;
    if constexpr (EPI == 0) {
      unsigned int lo = cvtpk(fmaxf(acc[ot][0], 0.f), fmaxf(acc[ot][1], 0.f));
      unsigned int hi = cvtpk(fmaxf(acc[ot][2], 0.f), fmaxf(acc[ot][3], 0.f));
      unsigned short* op = Ds + lr * DSTR + DOFF + o0 + quad*4;
      if constexpr ((DOFF & 3) == 0) {
        *(unsigned long long*)op = (unsigned long long)lo | ((unsigned long long)hi << 32);
      } else {
        *(unsigned int*)op       = lo;
        *(unsigned int*)(op + 2) = hi;
      }
    } else {
#pragma unroll
      for (int rr = 0; rr < 4; ++rr) {
        float v = fmaxf(acc[ot][rr], 0.f);
        v = fmaxf(v, __shfl_xor(v, 1, 64));
        v = fmaxf(v, __shfl_xor(v, 2, 64));
        v = fmaxf(v, __shfl_xor(v, 4, 64));
        v = fmaxf(v, __shfl_xor(v, 8, 64));
        if (lr == 0)
          atomicMax(&outmax[b * FF + o0 + quad*4 + rr], __float_as_uint(v));
      }
    }
  }
}

// ---------------- K6: fused gp chain + last-block output convert ----------------
__global__ __launch_bounds__(1024) void k_gp(
    const unsigned int* __restrict__ pooled, const float* __restrict__ feat0,
    const int* __restrict__ rowflag, const float* __restrict__ noderot,
    const unsigned short* __restrict__ Wb, const float* __restrict__ Fb,
    const int* __restrict__ flag, int* __restrict__ tick,
    unsigned int* __restrict__ outmax, void* __restrict__ out) {
  __shared__ unsigned short G3[16 * 648];   // [j][0..129]=g_in, [130..641]=h3
  __shared__ unsigned short H1[16 * 264];   // stride 264: 132 dw == 4 mod 32
  __shared__ unsigned short H2[16 * 264];
  __shared__ int lastf;
  const unsigned short* gW0 = Wb + 28928;   // 256 x 130
  const unsigned short* gW1 = Wb + 62208;   // 256 x 256
  const unsigned short* gW2 = Wb + 127744;  // 512 x 256
  const unsigned short* gW3 = Wb + 258816;  // 512 x 642
  int tid = threadIdx.x, lane = tid & 63, wv = tid >> 6;   // 16 waves
  int quad = lane >> 4, lr = lane & 15;
  int c0 = blockIdx.x * 16;
  int br = c0 >> 6, b = br >> 2;
  // ---- build g_in columns ----
  {
    int j = tid >> 6, oq = (tid & 63) << 1;   // 16 cols x 64 thr, 2 o's each
    int col = c0 + j, m = col & 63;
    int fl = rowflag[b * 64 + m];
    float v0 = __uint_as_float(pooled[((long)col << 7) + oq]);
    float v1 = __uint_as_float(pooled[((long)col << 7) + oq + 1]);
    if (!fl) { v0 = feat0[br * 128 + oq]; v1 = feat0[br * 128 + oq + 1]; }
    *(unsigned int*)&G3[j * 648 + 2 + oq] = cvtpk(v0, v1);
    if (tid < 32) {
      int jj = tid >> 1, o = tid & 1;
      int mm = (c0 + jj) & 63;
      G3[jj * 648 + o] = f2bf(noderot[(br * 2 + o) * 64 + mm]);
    }
  }
  __syncthreads();
  gp_layer<1, 130, 128, true,  264, 0,   0>(gW0, Fb + 512,  G3, 648, H1, wv, quad, lr, b, outmax);
  __syncthreads();
  gp_layer<1, 256, 256, false, 264, 0,   0>(gW1, Fb + 768,  H1, 264, H2, wv, quad, lr, b, outmax);
  __syncthreads();
  gp_layer<2, 256, 256, false, 648, 130, 0>(gW2, Fb + 1024, H2, 264, G3, wv, quad, lr, b, outmax);
  __syncthreads();
  gp_layer<2, 642, 640, true,  0,   0,   1>(gW3, Fb + 1536, G3, 648, nullptr, wv, quad, lr, b, outmax);
  // ---- last-block ticket: convert outmax -> out (replaces k_out dispatch) ----
  __threadfence();
  if (tid == 0) lastf = (atomicAdd(tick, 1) == 63) ? 1 : 0;
  __syncthreads();
  if (lastf) {
    int isbf = flag[0];
    for (int t = tid; t < 2048; t += 1024) {
      unsigned int u = atomicMax(&outmax[t], 0u);   // device-coherent read
      float v = __uint_as_float(u);
      if (isbf) ((unsigned short*)out)[t] = f2bf(v);
      else      ((float*)out)[t] = v;
    }
  }
}

// ---------------- host ----------------
extern "C" void kernel_launch(void* const* d_in, const int* in_sizes, int n_in,
                              void* d_out, int out_size, void* d_ws, size_t ws_size,
                              hipStream_t stream) {
  const void* x    = d_in[0];
  const void* node = d_in[2];

  // workspace layout (zeroed region first)
  char* ws = (char*)d_ws;
  int*            flag    = (int*)(ws + 0);              //    256 (4 used; tick @ +128)
  int*            tick    = (int*)(ws + 128);            //      4 (zeroed each launch)
  float*          csum    = (float*)(ws + 256);          //   3072
  unsigned int*   outmax  = (unsigned int*)(ws + 3328);  //   8192
  unsigned int*   pooled  = (unsigned int*)(ws + 11520); // 524288
  // ---- end of memset region (535808 B) ----
  int*            idx     = (int*)(ws + 535808);         // 196608
  int*            blkcnt  = (int*)(ws + 732416);         //  16384
  float*          noderot = (float*)(ws + 766208);       //   8192
  int*            rowflag = (int*)(ws + 774400);         //   1024
  int*            sorted  = (int*)(ws + 775424);         // 196608
  float*          feat0   = (float*)(ws + 972032);       //   8192
  unsigned short* fW3p    = (unsigned short*)(ws + 980224);   // 40960 (128x160 bf16)
  float*          Fb      = (float*)(ws + 1021184);      //   8192 (2048 f32)
  unsigned short* Wb      = (unsigned short*)(ws + 3355904);  // 1175040

  hipMemsetAsync(ws, 0, 535808, stream);

  WPtrs wp;
  wp.p[0]=d_in[6];  wp.p[1]=d_in[8];  wp.p[2]=d_in[10];             // fpW1,fpW2,fpW3
  wp.p[3]=d_in[12]; wp.p[4]=d_in[14]; wp.p[5]=d_in[16]; wp.p[6]=d_in[18]; // gpW0..3
  wp.p[7]=d_in[4];                                                   // fpW0
  wp.p[8]=d_in[5];  wp.p[9]=d_in[7];  wp.p[10]=d_in[9]; wp.p[11]=d_in[11]; // fpb0..3
  wp.p[12]=d_in[13]; wp.p[13]=d_in[15]; wp.p[14]=d_in[17]; wp.p[15]=d_in[19]; // gpb0..3

  // merged detect + cvt(x8) + assign: blocks [0,298) cvt, [298,362) assign
  k_front<<<362, 256, 0, stream>>>(x, node, wp, flag, Wb, fW3p, Fb, idx, csum, blkcnt);
  // merged means + scatter
  k_scatter2<<<64, 256, 0, stream>>>(csum, blkcnt, idx, sorted, noderot, rowflag);
  // fp block (r4-proven) + gp-weight L2 warm
  k_fused<<<dim3(192, 16), 256, 0, stream>>>(x, sorted, idx, noderot, flag,
                                             Wb, fW3p, Fb, pooled, feat0);
  // fused gp chain (chunked loads) + ticket-gated output convert
  k_gp<<<64, 1024, 0, stream>>>(pooled, feat0, rowflag, noderot, Wb, Fb,
                                flag, tick, outmax, d_out);
}

// Round 9
// 189.286 us; speedup vs baseline: 1.0934x; 1.0934x over previous
//
#include <hip/hip_runtime.h>
#include <stdint.h>

// ---------------- problem constants ----------------
#define BB 4
#define RR 4
#define NN 4096
#define MM 64
#define KK 3
#define KNN 12288           // KK*NN
#define BRR 16              // BB*RR
#define FF 512

typedef short bf16x8 __attribute__((ext_vector_type(8)));
typedef float f32x4 __attribute__((ext_vector_type(4)));

__device__ __forceinline__ float bf2f(unsigned int u) {
  union { unsigned int i; float f; } v; v.i = u << 16; return v.f;
}
__device__ __forceinline__ unsigned short f2bf(float f) {
  union { float f; unsigned int i; } v; v.f = f;
  unsigned int x = v.i;
  return (unsigned short)((x + 0x7fffu + ((x >> 16) & 1u)) >> 16);
}
// packed RNE f32x2 -> bf16x2 (T12 recipe; no builtin on gfx950)
__device__ __forceinline__ unsigned int cvtpk(float a, float b) {
  unsigned int r;
  asm("v_cvt_pk_bf16_f32 %0, %1, %2" : "=v"(r) : "v"(a), "v"(b));
  return r;
}
// dtype-adaptive load: isbf=1 -> buffer is bf16 ushorts; else fp32 floats
__device__ __forceinline__ float ldf(const void* p, long i, int isbf) {
  if (isbf) return bf2f(((const unsigned short*)p)[i]);
  return ((const float*)p)[i];
}
// LDS bank-conflict swizzles (XOR short-offset bits 3..4 with col bits 3..4).
__device__ __forceinline__ int hsw(int col, int so) { return col * 72  + (so ^ (col & 24)); }
__device__ __forceinline__ int csw(int col, int so) { return col * 168 + (so ^ (col & 24)); } // so < 160

struct WPtrs { const void* p[16]; };
// 0..6: fpW1,fpW2,fpW3,gpW0,gpW1,gpW2,gpW3 (-> Wb bf16)
// 7..15: fpW0,fpb0,fpb1,fpb2,fpb3,gpb0,gpb1,gpb2,gpb3 (-> Fb f32)
// Fb float layout: fW0@0(128) fb0@128(64) fb1@192(64) fb2@256(128) fb3@384(128)
//                  gpb0@512(256) gpb1@768(256) gpb2@1024(512) gpb3@1536(512)

// ---------------- K0: merged dtype-probe + weight-cvt(x8 vec) + assign ----------------
__global__ __launch_bounds__(256) void k_front(
    const void* __restrict__ x, const void* __restrict__ node, WPtrs wp,
    int* __restrict__ flag, unsigned short* __restrict__ Wb,
    unsigned short* __restrict__ fW3p, float* __restrict__ Fb,
    int* __restrict__ idx, float* __restrict__ csum, int* __restrict__ blkcnt) {
  __shared__ int bad;
  __shared__ float nd[2][64];
  __shared__ float cs[192];   // [m][{sx,sy,cnt}]
  int tid = threadIdx.x;
  if (tid == 0) bad = 0;
  __syncthreads();
  {
    const unsigned short* xs = (const unsigned short*)x;
    int cnt = 0;
    for (int i = tid; i < 1024; i += 256) {
      unsigned short u = xs[i * 2];
      int e = (u >> 7) & 0xFF;
      if (e >= 0x90 || (e > 0 && e <= 0x50)) ++cnt;
    }
    atomicAdd(&bad, cnt);
  }
  __syncthreads();
  int isbf = (bad < 100) ? 1 : 0;
  if (blockIdx.x == 0 && tid == 0) flag[0] = isbf;

  if (blockIdx.x < 298) {
    const int e0=4096, e1=12288, e2=28928, e3=62208, e4=127744, e5=258816, e6=587520;
    int t8 = blockIdx.x * 256 + tid;
    if (t8 < 73440) {
      int base = t8 * 8;
      int s, segb;
      if      (base < e0) { s=0; segb=0;  }
      else if (base < e1) { s=1; segb=e0; }
      else if (base < e2) { s=2; segb=e1; }
      else if (base < e3) { s=3; segb=e2; }
      else if (base < e4) { s=4; segb=e3; }
      else if (base < e5) { s=5; segb=e4; }
      else                { s=6; segb=e5; }
      int local = base - segb;
      union { bf16x8 v; unsigned int u[4]; } ov;
      if (isbf) {
        ov.v = *(const bf16x8*)((const unsigned short*)wp.p[s] + local);
      } else {
        const float4* fp = (const float4*)((const float*)wp.p[s] + local);
        float4 f0 = fp[0], f1 = fp[1];
        ov.u[0] = cvtpk(f0.x, f0.y); ov.u[1] = cvtpk(f0.z, f0.w);
        ov.u[2] = cvtpk(f1.x, f1.y); ov.u[3] = cvtpk(f1.z, f1.w);
      }
      *(bf16x8*)(Wb + base) = ov.v;
    } else if (t8 < 76000) {
      int v = t8 - 73440;
      int base = v * 8;
      int o = v / 20, c = (v - o * 20) * 8;    // 160 = 20*8
      union { bf16x8 vv; unsigned short s8[8]; } ov;
#pragma unroll
      for (int j = 0; j < 8; ++j) {
        int cc = c + j;
        unsigned short u = 0;
        if (cc < 130) {
          long si = (long)o * 130 + cc;
          if (isbf) u = ((const unsigned short*)wp.p[2])[si];
          else      u = f2bf(((const float*)wp.p[2])[si]);
        }
        ov.s8[j] = u;
      }
      *(bf16x8*)(fW3p + base) = ov.vv;
    } else if (t8 < 76256) {
      int l = (t8 - 76000) * 8;
      const void* src; int off;
      if      (l < 128)  { src = wp.p[7];  off = 0;    }
      else if (l < 192)  { src = wp.p[8];  off = 128;  }
      else if (l < 256)  { src = wp.p[9];  off = 192;  }
      else if (l < 384)  { src = wp.p[10]; off = 256;  }
      else if (l < 512)  { src = wp.p[11]; off = 384;  }
      else if (l < 768)  { src = wp.p[12]; off = 512;  }
      else if (l < 1024) { src = wp.p[13]; off = 768;  }
      else if (l < 1536) { src = wp.p[14]; off = 1024; }
      else               { src = wp.p[15]; off = 1536; }
#pragma unroll
      for (int j = 0; j < 8; ++j) Fb[l + j] = ldf(src, l + j - off, isbf);
    }
    return;
  }
  // ---- assign ----
  int bi = blockIdx.x - 298;         // b*16 + chunk
  int b = bi >> 4;
  int n = ((bi & 15) << 8) + tid;
  if (tid < 128) nd[tid >> 6][tid & 63] = ldf(node, b * 128 + tid, isbf);
  if (tid < 192) cs[tid] = 0.f;
  __syncthreads();
  float x0 = ldf(x, b * 8192 + n, isbf);
  float x1 = ldf(x, b * 8192 + 4096 + n, isbf);
  float d0 = 1e30f, d1 = 1e30f, d2 = 1e30f;
  int m0 = 0, m1 = 0, m2 = 0;
#pragma unroll 8
  for (int m = 0; m < 64; ++m) {
    float dx = x0 - nd[0][m];
    float dy = x1 - nd[1][m];
    float d = __fmul_rn(dx, dx) + __fmul_rn(dy, dy);   // no contraction: match ref
    if (d < d0)      { d2=d1; m2=m1; d1=d0; m1=m0; d0=d; m0=m; }
    else if (d < d1) { d2=d1; m2=m1; d1=d;  m1=m; }
    else if (d < d2) { d2=d;  m2=m; }
  }
  long base = ((long)b * NN + n) * 3;
  idx[base] = m0; idx[base + 1] = m1; idx[base + 2] = m2;
  atomicAdd(&cs[m0*3+0], x0); atomicAdd(&cs[m0*3+1], x1); atomicAdd(&cs[m0*3+2], 1.f);
  atomicAdd(&cs[m1*3+0], x0); atomicAdd(&cs[m1*3+1], x1); atomicAdd(&cs[m1*3+2], 1.f);
  atomicAdd(&cs[m2*3+0], x0); atomicAdd(&cs[m2*3+1], x1); atomicAdd(&cs[m2*3+2], 1.f);
  __syncthreads();
  if (tid < 192) atomicAdd(&csum[b * 192 + tid], cs[tid]);
  if (tid < 64) blkcnt[bi * 64 + tid] = (int)cs[tid*3 + 2];
}

// ---------------- K1: merged means + counting-sort scatter ----------------
__global__ __launch_bounds__(256) void k_scatter2(
    const float* __restrict__ csum, const int* __restrict__ blkcnt,
    const int* __restrict__ idx, int* __restrict__ sorted,
    float* __restrict__ noderot, int* __restrict__ rowflag) {
  __shared__ int scnt[64];
  __shared__ int soff[64];
  __shared__ int lc[64];
  int tid = threadIdx.x;
  int blk = blockIdx.x;              // b*16 + chunk (matches k_front assign)
  int b = blk >> 4, chunk = blk & 15;
  if (tid < 64) scnt[tid] = (int)csum[b*192 + tid*3 + 2];
  __syncthreads();
  if (tid < 64) {
    int m = tid, acc = 0;
    for (int mm = 0; mm < m; ++mm) acc += scnt[mm];          // counts are exact floats
    for (int c = 0; c < chunk; ++c) acc += blkcnt[(b*16 + c)*64 + m];
    soff[m] = acc;
    lc[m] = 0;
    if (chunk == 0) {
      float s0 = csum[b*192 + m*3], s1 = csum[b*192 + m*3 + 1], cc = csum[b*192 + m*3 + 2];
      float mx = s0 / (cc + 1e-5f);
      float my = s1 / (cc + 1e-5f);
      rowflag[b*64 + m] = (cc > 0.f) ? 1 : 0;
      for (int r = 0; r < 4; ++r) {
        float th = 1.5707964f * (float)r;
        float cr = cosf(th), sr = sinf(th);
        noderot[((b*4 + r)*2 + 0)*64 + m] = cr*mx - sr*my;
        noderot[((b*4 + r)*2 + 1)*64 + m] = sr*mx + cr*my;
      }
    }
  }
  __syncthreads();
  int n = ((blk & 15) << 8) + tid;
#pragma unroll
  for (int kk = 0; kk < 3; ++kk) {
    int m = idx[((long)b * NN + n) * 3 + kk];
    int pos = atomicAdd(&lc[m], 1);                 // LDS atomic, order irrelevant
    sorted[b * KNN + soff[m] + pos] = (m << 12) | n;
  }
}

// ---------------- K5: fused fp block (r4-exact, proven 49.5us) ----------------
__global__ __launch_bounds__(256) void k_fused(
    const void* __restrict__ x, const int* __restrict__ sorted,
    const int* __restrict__ idx, const float* __restrict__ noderot,
    const int* __restrict__ flag, const unsigned short* __restrict__ Wb,
    const unsigned short* __restrict__ fW3p, const float* __restrict__ Fb,
    unsigned int* __restrict__ pooled, float* __restrict__ feat0) {
  __shared__ unsigned short Cs[64 * 168];   // [col][0..1]=xdec,[2..129]=h2,[130..159]=0; later [0..127]=feat
  __shared__ unsigned short Hs[64 * 72];    // h1
  __shared__ int mcol[64];                  // m | (is_col0 << 8)
  const unsigned short* fW1 = Wb;           // 64x64
  const unsigned short* fW2 = Wb + 4096;    // 128x64
  int isbf = flag[0];
  int tid = threadIdx.x, lane = tid & 63, wv = tid >> 6;
  int quad = lane >> 4, lr = lane & 15;
  int br = blockIdx.y, b = br >> 2, r = br & 3;
  int o1 = wv * 16;
  if (tid < 64) {
    int e = sorted[b * KNN + blockIdx.x * 64 + tid];
    int m = e >> 12, n = e & 4095;
    int isz = (n == 0 && m == idx[(long)b * NN * 3]) ? 256 : 0;
    mcol[tid] = m | isz;
    float x0 = ldf(x, b*8192 + n, isbf), x1 = ldf(x, b*8192 + 4096 + n, isbf);
    float th = 1.5707964f * (float)r;
    float cr = cosf(th), sr = sinf(th);
    float xd0 = (cr*x0 - sr*x1) - noderot[(br*2 + 0)*64 + m];
    float xd1 = (sr*x0 + cr*x1) - noderot[(br*2 + 1)*64 + m];
    *(unsigned int*)&Cs[csw(tid, 0)] = cvtpk(xd0, xd1);
  }
  // zero logical channels 130..159 (once per block; never overwritten)
  for (int z = tid; z < 960; z += 256) {
    int col = z / 15, l = 130 + (z - col * 15) * 2;
    *(unsigned int*)&Cs[csw(col, l)] = 0u;
  }
  __syncthreads();
  // ----- layer0 (2 -> 64), VALU, weights/bias from f32 table -----
  {
    int col = tid & 63, og = (tid >> 6) << 4;
    unsigned int xu = *(unsigned int*)&Cs[csw(col, 0)];
    float fx0 = bf2f(xu & 0xffff), fx1 = bf2f(xu >> 16);
    const float2* w2 = (const float2*)Fb;
    float hv[16];
#pragma unroll
    for (int j = 0; j < 16; ++j) {
      int o = og + j;
      float2 w = w2[o];
      float h = Fb[128 + o] + w.x * fx0 + w.y * fx1;
      hv[j] = fmaxf(h, 0.f);
    }
    union { bf16x8 v; unsigned int u[4]; } o8[2];
#pragma unroll
    for (int j = 0; j < 16; j += 2) o8[j >> 3].u[(j & 7) >> 1] = cvtpk(hv[j], hv[j+1]);
    *(bf16x8*)&Hs[hsw(col, og)]     = o8[0].v;
    *(bf16x8*)&Hs[hsw(col, og + 8)] = o8[1].v;
  }
  __syncthreads();
  // ----- layer1 (64 -> 64), MFMA -----
  {
    f32x4 acc[4];
#pragma unroll
    for (int nt = 0; nt < 4; ++nt)
      acc[nt] = (f32x4){Fb[192 + o1 + quad*4], Fb[192 + o1 + quad*4 + 1],
                        Fb[192 + o1 + quad*4 + 2], Fb[192 + o1 + quad*4 + 3]};
#pragma unroll
    for (int ks2 = 0; ks2 < 2; ++ks2) {
      bf16x8 a = *(const bf16x8*)(fW1 + (o1 + lr)*64 + ks2*32 + quad*8);
#pragma unroll
      for (int nt = 0; nt < 4; ++nt) {
        bf16x8 bf = *(bf16x8*)&Hs[hsw(nt*16 + lr, ks2*32 + quad*8)];
        acc[nt] = __builtin_amdgcn_mfma_f32_16x16x32_bf16(a, bf, acc[nt], 0, 0, 0);
      }
    }
    __syncthreads();  // everyone done READING Hs
#pragma unroll
    for (int nt = 0; nt < 4; ++nt) {
      int col = nt*16 + lr;
      unsigned int lo = cvtpk(fmaxf(acc[nt][0], 0.f), fmaxf(acc[nt][1], 0.f));
      unsigned int hi = cvtpk(fmaxf(acc[nt][2], 0.f), fmaxf(acc[nt][3], 0.f));
      *(unsigned long long*)&Hs[hsw(col, o1 + quad*4)] =
          (unsigned long long)lo | ((unsigned long long)hi << 32);
    }
  }
  __syncthreads();
  // ----- layer2 (64 -> 128), MFMA, output into Cs logical [2..129] -----
#pragma unroll
  for (int p2 = 0; p2 < 2; ++p2) {
    int o0 = p2*64 + o1;
    f32x4 acc[4];
#pragma unroll
    for (int nt = 0; nt < 4; ++nt)
      acc[nt] = (f32x4){Fb[256 + o0 + quad*4], Fb[256 + o0 + quad*4 + 1],
                        Fb[256 + o0 + quad*4 + 2], Fb[256 + o0 + quad*4 + 3]};
#pragma unroll
    for (int ks2 = 0; ks2 < 2; ++ks2) {
      bf16x8 a = *(const bf16x8*)(fW2 + (o0 + lr)*64 + ks2*32 + quad*8);
#pragma unroll
      for (int nt = 0; nt < 4; ++nt) {
        bf16x8 bf = *(bf16x8*)&Hs[hsw(nt*16 + lr, ks2*32 + quad*8)];
        acc[nt] = __builtin_amdgcn_mfma_f32_16x16x32_bf16(a, bf, acc[nt], 0, 0, 0);
      }
    }
#pragma unroll
    for (int nt = 0; nt < 4; ++nt) {
      int col = nt*16 + lr;
      int o = o0 + quad*4;
      unsigned int w0 = cvtpk(fmaxf(acc[nt][0], 0.f), fmaxf(acc[nt][1], 0.f));
      unsigned int w1 = cvtpk(fmaxf(acc[nt][2], 0.f), fmaxf(acc[nt][3], 0.f));
      *(unsigned int*)&Cs[csw(col, 2 + o)] = w0;
      *(unsigned int*)&Cs[csw(col, 4 + o)] = w1;
    }
  }
  __syncthreads();
  // ----- layer3 (K padded to 160): 5 clean MFMA steps, no scalar tail -----
  f32x4 acc3[2][4];
#pragma unroll
  for (int p3 = 0; p3 < 2; ++p3) {
    int o0 = p3*64 + o1;
#pragma unroll
    for (int nt = 0; nt < 4; ++nt)
      acc3[p3][nt] = (f32x4){Fb[384 + o0 + quad*4], Fb[384 + o0 + quad*4 + 1],
                             Fb[384 + o0 + quad*4 + 2], Fb[384 + o0 + quad*4 + 3]};
#pragma unroll
    for (int ks5 = 0; ks5 < 5; ++ks5) {
      bf16x8 a = *(const bf16x8*)(fW3p + (o0 + lr)*160 + ks5*32 + quad*8);
#pragma unroll
      for (int nt = 0; nt < 4; ++nt) {
        bf16x8 bf = *(bf16x8*)&Cs[csw(nt*16 + lr, ks5*32 + quad*8)];
        acc3[p3][nt] = __builtin_amdgcn_mfma_f32_16x16x32_bf16(a, bf, acc3[p3][nt], 0, 0, 0);
      }
    }
  }
  __syncthreads();   // ALL Cs reads complete before feat overwrite
#pragma unroll
  for (int p3 = 0; p3 < 2; ++p3) {
    int o0 = p3*64 + o1;
#pragma unroll
    for (int nt = 0; nt < 4; ++nt) {
      int col = nt*16 + lr;
      unsigned int lo = cvtpk(fmaxf(acc3[p3][nt][0], 0.f), fmaxf(acc3[p3][nt][1], 0.f));
      unsigned int hi = cvtpk(fmaxf(acc3[p3][nt][2], 0.f), fmaxf(acc3[p3][nt][3], 0.f));
      *(unsigned long long*)&Cs[csw(col, o0 + quad*4)] =
          (unsigned long long)lo | ((unsigned long long)hi << 32);
    }
  }
  __syncthreads();
  // ----- run-scan segment max: packed u32, integer max (bf16>=0 => u16 order) ---
  {
    int opair = tid & 63, h = tid >> 6;      // wave-uniform h: 4 waves x 16 cols
    int o0 = opair * 2;
    int c0 = h * 16;
    int curm = mcol[c0] & 255;
    unsigned int vlo = 0u, vhi = 0u;
    for (int c = c0; c < c0 + 16; ++c) {
      int mc = mcol[c];
      int mm = mc & 255;
      unsigned int u = *(unsigned int*)&Cs[csw(c, o0)];
      if (mm != curm) {
        atomicMax(&pooled[(((long)br*64 + curm) << 7) + o0],     vlo);
        atomicMax(&pooled[(((long)br*64 + curm) << 7) + o0 + 1], vhi);
        curm = mm; vlo = vhi = 0u;
      }
      vlo = max(vlo, u << 16);
      vhi = max(vhi, u & 0xffff0000u);
      if (mc & 256) {
        feat0[br*128 + o0]     = __uint_as_float(u << 16);
        feat0[br*128 + o0 + 1] = __uint_as_float(u & 0xffff0000u);
      }
    }
    atomicMax(&pooled[(((long)br*64 + curm) << 7) + o0],     vlo);
    atomicMax(&pooled[(((long)br*64 + curm) << 7) + o0 + 1], vhi);
  }
}

// ---------------- K6a..d: per-layer gp GEMM, 2D grid, LDS B-panel ----------------
// Block = NT*16 cols (one col-tile, all within one br) x 64 outs (4 waves x 16).
// Grids sized to ~256 blocks -> all CUs busy; per-block weight slice is 64 rows.
// GIN: build g_in [0..129] from pooled/feat0/noderot. INSTR>0: stage INSTR chans
// from Bg at Bs[HOFF..]. EPI 0: relu+bf16 -> Out[col*OSTR + o]. EPI 2: node/rot
// max + atomicMax(outmax) + ticket-gated final output convert (NBLK blocks).
template<int KW, int KWP, int KMAIN, bool REM2, bool GIN, int INSTR, int HOFF,
         int NT, int EPI, int NBLK>
__global__ __launch_bounds__(256) void k_gemm(
    const unsigned short* __restrict__ W, const float* __restrict__ bias,
    const unsigned int* __restrict__ pooled, const float* __restrict__ feat0,
    const int* __restrict__ rowflag, const float* __restrict__ noderot,
    const unsigned short* __restrict__ Bg, unsigned short* __restrict__ Out,
    int OSTR, unsigned int* __restrict__ outmax,
    const int* __restrict__ flag, int* __restrict__ tick, void* __restrict__ out) {
  __shared__ __align__(16) unsigned short Bs[NT * 16 * KWP];
  __shared__ int lastf;
  int tid = threadIdx.x, lane = tid & 63, wv = tid >> 6;
  int quad = lane >> 4, lr = lane & 15;
  int p0 = blockIdx.x * (NT * 16);
  int br = p0 >> 6, b = br >> 2;
  // ---- stage B panel ----
  if constexpr (GIN) {
    for (int i = tid; i < NT * 256; i += 256) {   // NT*16 cols x 16 groups of 8 ch
      int j = i >> 4, g = i & 15;
      int col = p0 + j, m = col & 63;
      int fl = rowflag[b * 64 + m];
      int o8 = g * 8;
      unsigned int wq[4];
#pragma unroll
      for (int q = 0; q < 4; ++q) {
        float v0, v1;
        if (fl) {
          v0 = __uint_as_float(pooled[((long)col << 7) + o8 + q*2]);
          v1 = __uint_as_float(pooled[((long)col << 7) + o8 + q*2 + 1]);
        } else {
          v0 = feat0[br * 128 + o8 + q*2];
          v1 = feat0[br * 128 + o8 + q*2 + 1];
        }
        wq[q] = cvtpk(v0, v1);
      }
#pragma unroll
      for (int q = 0; q < 4; ++q)
        *(unsigned int*)&Bs[j * KWP + 2 + o8 + q*2] = wq[q];   // byte off 4+16g+4q: u32-aligned
    }
    if (tid < NT * 32) {
      int j = tid >> 1, o = tid & 1;
      Bs[j * KWP + o] = f2bf(noderot[(br * 2 + o) * 64 + ((p0 + j) & 63)]);
    }
  }
  if constexpr (INSTR > 0) {
    constexpr int NG = INSTR / 8;
    for (int i = tid; i < NT * 16 * NG; i += 256) {
      int j = i / NG, g = i - j * NG;
      union { bf16x8 v; unsigned int u[4]; } t;
      t.v = *(const bf16x8*)&Bg[(long)(p0 + j) * INSTR + g * 8];
      if constexpr ((HOFF % 8) == 0) {
        *(bf16x8*)&Bs[j * KWP + HOFF + g * 8] = t.v;
      } else {
#pragma unroll
        for (int q = 0; q < 4; ++q)
          *(unsigned int*)&Bs[j * KWP + HOFF + g * 8 + q*2] = t.u[q];
      }
    }
  }
  __syncthreads();
  // ---- MFMA: wave = 16 outs x NT*16 cols ----
  int o0 = blockIdx.y * 64 + wv * 16;
  f32x4 acc[NT];
#pragma unroll
  for (int nt = 0; nt < NT; ++nt)
    acc[nt] = (f32x4){bias[o0 + quad*4], bias[o0 + quad*4 + 1],
                      bias[o0 + quad*4 + 2], bias[o0 + quad*4 + 3]};
  const unsigned short* arow = W + (long)(o0 + lr) * KW;
  for (int ks = 0; ks < KMAIN; ks += 32) {
    bf16x8 a;
    if constexpr ((KW % 8) == 0) {
      a = *(const bf16x8*)(arow + ks + quad*8);
    } else {
      union { bf16x8 v; unsigned int u[4]; } au;
      const unsigned int* ap = (const unsigned int*)(arow + ks + quad*8);  // 4B aligned
      au.u[0] = ap[0]; au.u[1] = ap[1]; au.u[2] = ap[2]; au.u[3] = ap[3];
      a = au.v;
    }
#pragma unroll
    for (int nt = 0; nt < NT; ++nt) {
      bf16x8 bf = *(bf16x8*)&Bs[(nt*16 + lr) * KWP + ks + quad*8];
      acc[nt] = __builtin_amdgcn_mfma_f32_16x16x32_bf16(a, bf, acc[nt], 0, 0, 0);
    }
  }
  if constexpr (REM2) {
#pragma unroll
    for (int rr = 0; rr < 4; ++rr) {
      int o = o0 + quad*4 + rr;
      unsigned int wu = *(const unsigned int*)(W + (long)o * KW + KMAIN);
      float w0 = bf2f(wu & 0xffff), w1 = bf2f(wu >> 16);
#pragma unroll
      for (int nt = 0; nt < NT; ++nt) {
        unsigned int bu = *(unsigned int*)&Bs[(nt*16 + lr) * KWP + KMAIN];
        acc[nt][rr] += w0 * bf2f(bu & 0xffff) + w1 * bf2f(bu >> 16);
      }
    }
  }
  if constexpr (EPI == 0) {
#pragma unroll
    for (int nt = 0; nt < NT; ++nt) {
      unsigned int lo = cvtpk(fmaxf(acc[nt][0], 0.f), fmaxf(acc[nt][1], 0.f));
      unsigned int hi = cvtpk(fmaxf(acc[nt][2], 0.f), fmaxf(acc[nt][3], 0.f));
      unsigned short* op = Out + (long)(p0 + nt*16 + lr) * OSTR + o0 + quad*4;
      *(unsigned long long*)op = (unsigned long long)lo | ((unsigned long long)hi << 32);
    }
  } else {
#pragma unroll
    for (int rr = 0; rr < 4; ++rr) {
      float v = acc[0][rr];
#pragma unroll
      for (int nt = 1; nt < NT; ++nt) v = fmaxf(v, acc[nt][rr]);
      v = fmaxf(v, 0.f);
      v = fmaxf(v, __shfl_xor(v, 1, 64));
      v = fmaxf(v, __shfl_xor(v, 2, 64));
      v = fmaxf(v, __shfl_xor(v, 4, 64));
      v = fmaxf(v, __shfl_xor(v, 8, 64));
      if (lr == 0)
        atomicMax(&outmax[b * FF + o0 + quad*4 + rr], __float_as_uint(v));
    }
    // ---- last-block ticket: convert outmax -> out ----
    __threadfence();
    if (tid == 0) lastf = (atomicAdd(tick, 1) == NBLK - 1) ? 1 : 0;
    __syncthreads();
    if (lastf) {
      int isbf = flag[0];
      for (int t = tid; t < 2048; t += 256) {
        unsigned int u = atomicMax(&outmax[t], 0u);   // device-coherent read
        float v = __uint_as_float(u);
        if (isbf) ((unsigned short*)out)[t] = f2bf(v);
        else      ((float*)out)[t] = v;
      }
    }
  }
}

// ---------------- host ----------------
extern "C" void kernel_launch(void* const* d_in, const int* in_sizes, int n_in,
                              void* d_out, int out_size, void* d_ws, size_t ws_size,
                              hipStream_t stream) {
  const void* x    = d_in[0];
  const void* node = d_in[2];

  // workspace layout (zeroed region first)
  char* ws = (char*)d_ws;
  int*            flag    = (int*)(ws + 0);              //    256 (4 used; tick @ +128)
  int*            tick    = (int*)(ws + 128);            //      4 (zeroed each launch)
  float*          csum    = (float*)(ws + 256);          //   3072
  unsigned int*   outmax  = (unsigned int*)(ws + 3328);  //   8192
  unsigned int*   pooled  = (unsigned int*)(ws + 11520); // 524288
  // ---- end of memset region (535808 B) ----
  int*            idx     = (int*)(ws + 535808);         // 196608
  int*            blkcnt  = (int*)(ws + 732416);         //  16384
  float*          noderot = (float*)(ws + 766208);       //   8192
  int*            rowflag = (int*)(ws + 774400);         //   1024
  int*            sorted  = (int*)(ws + 775424);         // 196608
  float*          feat0   = (float*)(ws + 972032);       //   8192
  unsigned short* fW3p    = (unsigned short*)(ws + 980224);   // 40960 (128x160 bf16)
  float*          Fb      = (float*)(ws + 1021184);      //   8192 (2048 f32)
  unsigned short* Hg3     = (unsigned short*)(ws + 1048576);  // 1048576 (1024x512 bf16)
  unsigned short* Hg1     = (unsigned short*)(ws + 2307328);  // 524288 (1024x256)
  unsigned short* Hg2     = (unsigned short*)(ws + 2831616);  // 524288 (1024x256)
  unsigned short* Wb      = (unsigned short*)(ws + 3355904);  // 1175040

  hipMemsetAsync(ws, 0, 535808, stream);

  WPtrs wp;
  wp.p[0]=d_in[6];  wp.p[1]=d_in[8];  wp.p[2]=d_in[10];             // fpW1,fpW2,fpW3
  wp.p[3]=d_in[12]; wp.p[4]=d_in[14]; wp.p[5]=d_in[16]; wp.p[6]=d_in[18]; // gpW0..3
  wp.p[7]=d_in[4];                                                   // fpW0
  wp.p[8]=d_in[5];  wp.p[9]=d_in[7];  wp.p[10]=d_in[9]; wp.p[11]=d_in[11]; // fpb0..3
  wp.p[12]=d_in[13]; wp.p[13]=d_in[15]; wp.p[14]=d_in[17]; wp.p[15]=d_in[19]; // gpb0..3

  const unsigned short* gW0 = Wb + 28928;   // 256 x 130
  const unsigned short* gW1 = Wb + 62208;   // 256 x 256
  const unsigned short* gW2 = Wb + 127744;  // 512 x 256
  const unsigned short* gW3 = Wb + 258816;  // 512 x 642

  // merged detect + cvt(x8) + assign: blocks [0,298) cvt, [298,362) assign
  k_front<<<362, 256, 0, stream>>>(x, node, wp, flag, Wb, fW3p, Fb, idx, csum, blkcnt);
  // merged means + scatter
  k_scatter2<<<64, 256, 0, stream>>>(csum, blkcnt, idx, sorted, noderot, rowflag);
  // fp block (r4-proven)
  k_fused<<<dim3(192, 16), 256, 0, stream>>>(x, sorted, idx, noderot, flag,
                                             Wb, fW3p, Fb, pooled, feat0);
  // gp chain: 4 per-layer GEMMs, 256-block grids, LDS B-panels
  k_gemm<130, 136, 128, true,  true,  0,   0,   1, 0, 0>
      <<<dim3(64, 4), 256, 0, stream>>>(gW0, Fb + 512, pooled, feat0, rowflag,
                                        noderot, nullptr, Hg1, 256, nullptr,
                                        flag, tick, nullptr);
  k_gemm<256, 264, 256, false, false, 256, 0,   1, 0, 0>
      <<<dim3(64, 4), 256, 0, stream>>>(gW1, Fb + 768, pooled, feat0, rowflag,
                                        noderot, Hg1, Hg2, 256, nullptr,
                                        flag, tick, nullptr);
  k_gemm<256, 264, 256, false, false, 256, 0,   2, 0, 0>
      <<<dim3(32, 8), 256, 0, stream>>>(gW2, Fb + 1024, pooled, feat0, rowflag,
                                        noderot, Hg2, Hg3, 512, nullptr,
                                        flag, tick, nullptr);
  k_gemm<642, 648, 640, true,  true,  512, 130, 2, 2, 256>
      <<<dim3(32, 8), 256, 0, stream>>>(gW3, Fb + 1536, pooled, feat0, rowflag,
                                        noderot, Hg3, nullptr, 0, outmax,
                                        flag, tick, d_out);
}

// Round 10
// 187.117 us; speedup vs baseline: 1.1061x; 1.0116x over previous
//
#include <hip/hip_runtime.h>
#include <stdint.h>

// ---------------- problem constants ----------------
#define BB 4
#define RR 4
#define NN 4096
#define MM 64
#define KK 3
#define KNN 12288           // KK*NN
#define BRR 16              // BB*RR
#define FF 512

typedef short bf16x8 __attribute__((ext_vector_type(8)));
typedef float f32x4 __attribute__((ext_vector_type(4)));

__device__ __forceinline__ float bf2f(unsigned int u) {
  union { unsigned int i; float f; } v; v.i = u << 16; return v.f;
}
__device__ __forceinline__ unsigned short f2bf(float f) {
  union { float f; unsigned int i; } v; v.f = f;
  unsigned int x = v.i;
  return (unsigned short)((x + 0x7fffu + ((x >> 16) & 1u)) >> 16);
}
// packed RNE f32x2 -> bf16x2 (T12 recipe; no builtin on gfx950)
__device__ __forceinline__ unsigned int cvtpk(float a, float b) {
  unsigned int r;
  asm("v_cvt_pk_bf16_f32 %0, %1, %2" : "=v"(r) : "v"(a), "v"(b));
  return r;
}
// dtype-adaptive load: isbf=1 -> buffer is bf16 ushorts; else fp32 floats
__device__ __forceinline__ float ldf(const void* p, long i, int isbf) {
  if (isbf) return bf2f(((const unsigned short*)p)[i]);
  return ((const float*)p)[i];
}
// LDS bank-conflict swizzles (XOR short-offset bits 3..4 with col bits 3..4).
__device__ __forceinline__ int hsw(int col, int so) { return col * 72  + (so ^ (col & 24)); }
__device__ __forceinline__ int csw(int col, int so) { return col * 168 + (so ^ (col & 24)); } // so < 160

struct WPtrs { const void* p[16]; };
// 0..6: fpW1,fpW2,fpW3,gpW0,gpW1,gpW2,gpW3 (-> Wb bf16)
// 7..15: fpW0,fpb0,fpb1,fpb2,fpb3,gpb0,gpb1,gpb2,gpb3 (-> Fb f32)
// Fb float layout: fW0@0(128) fb0@128(64) fb1@192(64) fb2@256(128) fb3@384(128)
//                  gpb0@512(256) gpb1@768(256) gpb2@1024(512) gpb3@1536(512)

// ---------------- K0: merged dtype-probe + weight-cvt(x8 vec) + assign ----------------
__global__ __launch_bounds__(256) void k_front(
    const void* __restrict__ x, const void* __restrict__ node, WPtrs wp,
    int* __restrict__ flag, unsigned short* __restrict__ Wb,
    unsigned short* __restrict__ fW3p, float* __restrict__ Fb,
    int* __restrict__ idx, float* __restrict__ csum, int* __restrict__ blkcnt) {
  __shared__ int bad;
  __shared__ float nd[2][64];
  __shared__ float cs[192];   // [m][{sx,sy,cnt}]
  int tid = threadIdx.x;
  if (tid == 0) bad = 0;
  __syncthreads();
  {
    const unsigned short* xs = (const unsigned short*)x;
    int cnt = 0;
    for (int i = tid; i < 1024; i += 256) {
      unsigned short u = xs[i * 2];
      int e = (u >> 7) & 0xFF;
      if (e >= 0x90 || (e > 0 && e <= 0x50)) ++cnt;
    }
    atomicAdd(&bad, cnt);
  }
  __syncthreads();
  int isbf = (bad < 100) ? 1 : 0;
  if (blockIdx.x == 0 && tid == 0) flag[0] = isbf;

  if (blockIdx.x < 298) {
    const int e0=4096, e1=12288, e2=28928, e3=62208, e4=127744, e5=258816, e6=587520;
    int t8 = blockIdx.x * 256 + tid;
    if (t8 < 73440) {
      int base = t8 * 8;
      int s, segb;
      if      (base < e0) { s=0; segb=0;  }
      else if (base < e1) { s=1; segb=e0; }
      else if (base < e2) { s=2; segb=e1; }
      else if (base < e3) { s=3; segb=e2; }
      else if (base < e4) { s=4; segb=e3; }
      else if (base < e5) { s=5; segb=e4; }
      else                { s=6; segb=e5; }
      int local = base - segb;
      union { bf16x8 v; unsigned int u[4]; } ov;
      if (isbf) {
        ov.v = *(const bf16x8*)((const unsigned short*)wp.p[s] + local);
      } else {
        const float4* fp = (const float4*)((const float*)wp.p[s] + local);
        float4 f0 = fp[0], f1 = fp[1];
        ov.u[0] = cvtpk(f0.x, f0.y); ov.u[1] = cvtpk(f0.z, f0.w);
        ov.u[2] = cvtpk(f1.x, f1.y); ov.u[3] = cvtpk(f1.z, f1.w);
      }
      *(bf16x8*)(Wb + base) = ov.v;
    } else if (t8 < 76000) {
      int v = t8 - 73440;
      int base = v * 8;
      int o = v / 20, c = (v - o * 20) * 8;    // 160 = 20*8
      union { bf16x8 vv; unsigned short s8[8]; } ov;
#pragma unroll
      for (int j = 0; j < 8; ++j) {
        int cc = c + j;
        unsigned short u = 0;
        if (cc < 130) {
          long si = (long)o * 130 + cc;
          if (isbf) u = ((const unsigned short*)wp.p[2])[si];
          else      u = f2bf(((const float*)wp.p[2])[si]);
        }
        ov.s8[j] = u;
      }
      *(bf16x8*)(fW3p + base) = ov.vv;
    } else if (t8 < 76256) {
      int l = (t8 - 76000) * 8;
      const void* src; int off;
      if      (l < 128)  { src = wp.p[7];  off = 0;    }
      else if (l < 192)  { src = wp.p[8];  off = 128;  }
      else if (l < 256)  { src = wp.p[9];  off = 192;  }
      else if (l < 384)  { src = wp.p[10]; off = 256;  }
      else if (l < 512)  { src = wp.p[11]; off = 384;  }
      else if (l < 768)  { src = wp.p[12]; off = 512;  }
      else if (l < 1024) { src = wp.p[13]; off = 768;  }
      else if (l < 1536) { src = wp.p[14]; off = 1024; }
      else               { src = wp.p[15]; off = 1536; }
#pragma unroll
      for (int j = 0; j < 8; ++j) Fb[l + j] = ldf(src, l + j - off, isbf);
    }
    return;
  }
  // ---- assign ----
  int bi = blockIdx.x - 298;         // b*16 + chunk
  int b = bi >> 4;
  int n = ((bi & 15) << 8) + tid;
  if (tid < 128) nd[tid >> 6][tid & 63] = ldf(node, b * 128 + tid, isbf);
  if (tid < 192) cs[tid] = 0.f;
  __syncthreads();
  float x0 = ldf(x, b * 8192 + n, isbf);
  float x1 = ldf(x, b * 8192 + 4096 + n, isbf);
  float d0 = 1e30f, d1 = 1e30f, d2 = 1e30f;
  int m0 = 0, m1 = 0, m2 = 0;
#pragma unroll 8
  for (int m = 0; m < 64; ++m) {
    float dx = x0 - nd[0][m];
    float dy = x1 - nd[1][m];
    float d = __fmul_rn(dx, dx) + __fmul_rn(dy, dy);   // no contraction: match ref
    if (d < d0)      { d2=d1; m2=m1; d1=d0; m1=m0; d0=d; m0=m; }
    else if (d < d1) { d2=d1; m2=m1; d1=d;  m1=m; }
    else if (d < d2) { d2=d;  m2=m; }
  }
  long base = ((long)b * NN + n) * 3;
  idx[base] = m0; idx[base + 1] = m1; idx[base + 2] = m2;
  atomicAdd(&cs[m0*3+0], x0); atomicAdd(&cs[m0*3+1], x1); atomicAdd(&cs[m0*3+2], 1.f);
  atomicAdd(&cs[m1*3+0], x0); atomicAdd(&cs[m1*3+1], x1); atomicAdd(&cs[m1*3+2], 1.f);
  atomicAdd(&cs[m2*3+0], x0); atomicAdd(&cs[m2*3+1], x1); atomicAdd(&cs[m2*3+2], 1.f);
  __syncthreads();
  if (tid < 192) atomicAdd(&csum[b * 192 + tid], cs[tid]);
  if (tid < 64) blkcnt[bi * 64 + tid] = (int)cs[tid*3 + 2];
}

// ---------------- K1: merged means + counting-sort scatter ----------------
__global__ __launch_bounds__(256) void k_scatter2(
    const float* __restrict__ csum, const int* __restrict__ blkcnt,
    const int* __restrict__ idx, int* __restrict__ sorted,
    float* __restrict__ noderot, int* __restrict__ rowflag) {
  __shared__ int scnt[64];
  __shared__ int soff[64];
  __shared__ int lc[64];
  int tid = threadIdx.x;
  int blk = blockIdx.x;              // b*16 + chunk (matches k_front assign)
  int b = blk >> 4, chunk = blk & 15;
  if (tid < 64) scnt[tid] = (int)csum[b*192 + tid*3 + 2];
  __syncthreads();
  if (tid < 64) {
    int m = tid, acc = 0;
    for (int mm = 0; mm < m; ++mm) acc += scnt[mm];          // counts are exact floats
    for (int c = 0; c < chunk; ++c) acc += blkcnt[(b*16 + c)*64 + m];
    soff[m] = acc;
    lc[m] = 0;
    if (chunk == 0) {
      float s0 = csum[b*192 + m*3], s1 = csum[b*192 + m*3 + 1], cc = csum[b*192 + m*3 + 2];
      float mx = s0 / (cc + 1e-5f);
      float my = s1 / (cc + 1e-5f);
      rowflag[b*64 + m] = (cc > 0.f) ? 1 : 0;
      for (int r = 0; r < 4; ++r) {
        float th = 1.5707964f * (float)r;
        float cr = cosf(th), sr = sinf(th);
        noderot[((b*4 + r)*2 + 0)*64 + m] = cr*mx - sr*my;
        noderot[((b*4 + r)*2 + 1)*64 + m] = sr*mx + cr*my;
      }
    }
  }
  __syncthreads();
  int n = ((blk & 15) << 8) + tid;
#pragma unroll
  for (int kk = 0; kk < 3; ++kk) {
    int m = idx[((long)b * NN + n) * 3 + kk];
    int pos = atomicAdd(&lc[m], 1);                 // LDS atomic, order irrelevant
    sorted[b * KNN + soff[m] + pos] = (m << 12) | n;
  }
}

// ---------------- K5: fused fp block — TWO 64-col groups per block ----------------
// grid (96, 16), 512 threads (8 waves). Group g = wv>>2 processes cols
// [g*64, g*64+64) of column-tile blockIdx.x*128. Per-group code is byte-
// equivalent to the proven r4 kernel; barriers shared (groups symmetric).
// Halves block count and barriers-per-unit-work; 2 blocks/CU = 16 waves.
__global__ __launch_bounds__(512) void k_fused(
    const void* __restrict__ x, const int* __restrict__ sorted,
    const int* __restrict__ idx, const float* __restrict__ noderot,
    const int* __restrict__ flag, const unsigned short* __restrict__ Wb,
    const unsigned short* __restrict__ fW3p, const float* __restrict__ Fb,
    unsigned int* __restrict__ pooled, float* __restrict__ feat0) {
  __shared__ unsigned short Cs[128 * 168];  // [col][0..1]=xdec,[2..129]=h2,[130..159]=0; later [0..127]=feat
  __shared__ unsigned short Hs[128 * 72];   // h1
  __shared__ int mcol[128];                 // m | (is_col0 << 8)
  const unsigned short* fW1 = Wb;           // 64x64
  const unsigned short* fW2 = Wb + 4096;    // 128x64
  int isbf = flag[0];
  int tid = threadIdx.x, lane = tid & 63, wv = tid >> 6;
  int quad = lane >> 4, lr = lane & 15;
  int br = blockIdx.y, b = br >> 2, r = br & 3;
  int cb = (wv >> 2) * 64;                  // group column base
  int o1 = (wv & 3) * 16;                   // wave's o-slice within group
  if (tid < 128) {
    int col = tid;
    int e = sorted[b * KNN + blockIdx.x * 128 + col];
    int m = e >> 12, n = e & 4095;
    int isz = (n == 0 && m == idx[(long)b * NN * 3]) ? 256 : 0;
    mcol[col] = m | isz;
    float x0 = ldf(x, b*8192 + n, isbf), x1 = ldf(x, b*8192 + 4096 + n, isbf);
    float th = 1.5707964f * (float)r;
    float cr = cosf(th), sr = sinf(th);
    float xd0 = (cr*x0 - sr*x1) - noderot[(br*2 + 0)*64 + m];
    float xd1 = (sr*x0 + cr*x1) - noderot[(br*2 + 1)*64 + m];
    *(unsigned int*)&Cs[csw(col, 0)] = cvtpk(xd0, xd1);
  }
  // zero logical channels 130..159 (once per block; never overwritten)
  for (int z = tid; z < 1920; z += 512) {
    int col = z / 15, l = 130 + (z - col * 15) * 2;
    *(unsigned int*)&Cs[csw(col, l)] = 0u;
  }
  __syncthreads();
  // ----- layer0 (2 -> 64), VALU, weights/bias from f32 table -----
  {
    int col = tid & 127, og = (tid >> 7) << 4;
    unsigned int xu = *(unsigned int*)&Cs[csw(col, 0)];
    float fx0 = bf2f(xu & 0xffff), fx1 = bf2f(xu >> 16);
    const float2* w2 = (const float2*)Fb;
    float hv[16];
#pragma unroll
    for (int j = 0; j < 16; ++j) {
      int o = og + j;
      float2 w = w2[o];
      float h = Fb[128 + o] + w.x * fx0 + w.y * fx1;
      hv[j] = fmaxf(h, 0.f);
    }
    union { bf16x8 v; unsigned int u[4]; } o8[2];
#pragma unroll
    for (int j = 0; j < 16; j += 2) o8[j >> 3].u[(j & 7) >> 1] = cvtpk(hv[j], hv[j+1]);
    *(bf16x8*)&Hs[hsw(col, og)]     = o8[0].v;
    *(bf16x8*)&Hs[hsw(col, og + 8)] = o8[1].v;
  }
  __syncthreads();
  // ----- layer1 (64 -> 64), MFMA -----
  {
    f32x4 acc[4];
#pragma unroll
    for (int nt = 0; nt < 4; ++nt)
      acc[nt] = (f32x4){Fb[192 + o1 + quad*4], Fb[192 + o1 + quad*4 + 1],
                        Fb[192 + o1 + quad*4 + 2], Fb[192 + o1 + quad*4 + 3]};
#pragma unroll
    for (int ks2 = 0; ks2 < 2; ++ks2) {
      bf16x8 a = *(const bf16x8*)(fW1 + (o1 + lr)*64 + ks2*32 + quad*8);
#pragma unroll
      for (int nt = 0; nt < 4; ++nt) {
        bf16x8 bf = *(bf16x8*)&Hs[hsw(cb + nt*16 + lr, ks2*32 + quad*8)];
        acc[nt] = __builtin_amdgcn_mfma_f32_16x16x32_bf16(a, bf, acc[nt], 0, 0, 0);
      }
    }
    __syncthreads();  // everyone done READING Hs
#pragma unroll
    for (int nt = 0; nt < 4; ++nt) {
      int col = cb + nt*16 + lr;
      unsigned int lo = cvtpk(fmaxf(acc[nt][0], 0.f), fmaxf(acc[nt][1], 0.f));
      unsigned int hi = cvtpk(fmaxf(acc[nt][2], 0.f), fmaxf(acc[nt][3], 0.f));
      *(unsigned long long*)&Hs[hsw(col, o1 + quad*4)] =
          (unsigned long long)lo | ((unsigned long long)hi << 32);
    }
  }
  __syncthreads();
  // ----- layer2 (64 -> 128), MFMA, output into Cs logical [2..129] -----
#pragma unroll
  for (int p2 = 0; p2 < 2; ++p2) {
    int o0 = p2*64 + o1;
    f32x4 acc[4];
#pragma unroll
    for (int nt = 0; nt < 4; ++nt)
      acc[nt] = (f32x4){Fb[256 + o0 + quad*4], Fb[256 + o0 + quad*4 + 1],
                        Fb[256 + o0 + quad*4 + 2], Fb[256 + o0 + quad*4 + 3]};
#pragma unroll
    for (int ks2 = 0; ks2 < 2; ++ks2) {
      bf16x8 a = *(const bf16x8*)(fW2 + (o0 + lr)*64 + ks2*32 + quad*8);
#pragma unroll
      for (int nt = 0; nt < 4; ++nt) {
        bf16x8 bf = *(bf16x8*)&Hs[hsw(cb + nt*16 + lr, ks2*32 + quad*8)];
        acc[nt] = __builtin_amdgcn_mfma_f32_16x16x32_bf16(a, bf, acc[nt], 0, 0, 0);
      }
    }
#pragma unroll
    for (int nt = 0; nt < 4; ++nt) {
      int col = cb + nt*16 + lr;
      int o = o0 + quad*4;
      unsigned int w0 = cvtpk(fmaxf(acc[nt][0], 0.f), fmaxf(acc[nt][1], 0.f));
      unsigned int w1 = cvtpk(fmaxf(acc[nt][2], 0.f), fmaxf(acc[nt][3], 0.f));
      *(unsigned int*)&Cs[csw(col, 2 + o)] = w0;
      *(unsigned int*)&Cs[csw(col, 4 + o)] = w1;
    }
  }
  __syncthreads();
  // ----- layer3 (K padded to 160): 5 clean MFMA steps, no scalar tail -----
  f32x4 acc3[2][4];
#pragma unroll
  for (int p3 = 0; p3 < 2; ++p3) {
    int o0 = p3*64 + o1;
#pragma unroll
    for (int nt = 0; nt < 4; ++nt)
      acc3[p3][nt] = (f32x4){Fb[384 + o0 + quad*4], Fb[384 + o0 + quad*4 + 1],
                             Fb[384 + o0 + quad*4 + 2], Fb[384 + o0 + quad*4 + 3]};
#pragma unroll
    for (int ks5 = 0; ks5 < 5; ++ks5) {
      bf16x8 a = *(const bf16x8*)(fW3p + (o0 + lr)*160 + ks5*32 + quad*8);
#pragma unroll
      for (int nt = 0; nt < 4; ++nt) {
        bf16x8 bf = *(bf16x8*)&Cs[csw(cb + nt*16 + lr, ks5*32 + quad*8)];
        acc3[p3][nt] = __builtin_amdgcn_mfma_f32_16x16x32_bf16(a, bf, acc3[p3][nt], 0, 0, 0);
      }
    }
  }
  __syncthreads();   // ALL Cs reads complete before feat overwrite
#pragma unroll
  for (int p3 = 0; p3 < 2; ++p3) {
    int o0 = p3*64 + o1;
#pragma unroll
    for (int nt = 0; nt < 4; ++nt) {
      int col = cb + nt*16 + lr;
      unsigned int lo = cvtpk(fmaxf(acc3[p3][nt][0], 0.f), fmaxf(acc3[p3][nt][1], 0.f));
      unsigned int hi = cvtpk(fmaxf(acc3[p3][nt][2], 0.f), fmaxf(acc3[p3][nt][3], 0.f));
      *(unsigned long long*)&Cs[csw(col, o0 + quad*4)] =
          (unsigned long long)lo | ((unsigned long long)hi << 32);
    }
  }
  __syncthreads();
  // ----- run-scan segment max: packed u32, integer max (bf16>=0 => u16 order) ---
  {
    int opair = tid & 63, h = tid >> 6;      // wave-uniform h: 8 waves x 16 cols
    int o0 = opair * 2;
    int c0 = h * 16;
    int curm = mcol[c0] & 255;
    unsigned int vlo = 0u, vhi = 0u;
    for (int c = c0; c < c0 + 16; ++c) {
      int mc = mcol[c];
      int mm = mc & 255;
      unsigned int u = *(unsigned int*)&Cs[csw(c, o0)];
      if (mm != curm) {
        atomicMax(&pooled[(((long)br*64 + curm) << 7) + o0],     vlo);
        atomicMax(&pooled[(((long)br*64 + curm) << 7) + o0 + 1], vhi);
        curm = mm; vlo = vhi = 0u;
      }
      vlo = max(vlo, u << 16);
      vhi = max(vhi, u & 0xffff0000u);
      if (mc & 256) {
        feat0[br*128 + o0]     = __uint_as_float(u << 16);
        feat0[br*128 + o0 + 1] = __uint_as_float(u & 0xffff0000u);
      }
    }
    atomicMax(&pooled[(((long)br*64 + curm) << 7) + o0],     vlo);
    atomicMax(&pooled[(((long)br*64 + curm) << 7) + o0 + 1], vhi);
  }
}

// ---------------- K6a..d: per-layer gp GEMM, 2D grid, LDS B-panel ----------------
// Block = NT*16 cols (one col-tile, all within one br) x 64 outs (4 waves x 16).
// Grids sized to ~256 blocks -> all CUs busy; per-block weight slice is 64 rows.
// GIN: build g_in [0..129] from pooled/feat0/noderot. INSTR>0: stage INSTR chans
// from Bg at Bs[HOFF..]. EPI 0: relu+bf16 -> Out[col*OSTR + o]. EPI 2: node/rot
// max + atomicMax(outmax) + ticket-gated final output convert (NBLK blocks).
template<int KW, int KWP, int KMAIN, bool REM2, bool GIN, int INSTR, int HOFF,
         int NT, int EPI, int NBLK>
__global__ __launch_bounds__(256) void k_gemm(
    const unsigned short* __restrict__ W, const float* __restrict__ bias,
    const unsigned int* __restrict__ pooled, const float* __restrict__ feat0,
    const int* __restrict__ rowflag, const float* __restrict__ noderot,
    const unsigned short* __restrict__ Bg, unsigned short* __restrict__ Out,
    int OSTR, unsigned int* __restrict__ outmax,
    const int* __restrict__ flag, int* __restrict__ tick, void* __restrict__ out) {
  __shared__ __align__(16) unsigned short Bs[NT * 16 * KWP];
  __shared__ int lastf;
  int tid = threadIdx.x, lane = tid & 63, wv = tid >> 6;
  int quad = lane >> 4, lr = lane & 15;
  int p0 = blockIdx.x * (NT * 16);
  int br = p0 >> 6, b = br >> 2;
  // ---- stage B panel ----
  if constexpr (GIN) {
    for (int i = tid; i < NT * 256; i += 256) {   // NT*16 cols x 16 groups of 8 ch
      int j = i >> 4, g = i & 15;
      int col = p0 + j, m = col & 63;
      int fl = rowflag[b * 64 + m];
      int o8 = g * 8;
      unsigned int wq[4];
#pragma unroll
      for (int q = 0; q < 4; ++q) {
        float v0, v1;
        if (fl) {
          v0 = __uint_as_float(pooled[((long)col << 7) + o8 + q*2]);
          v1 = __uint_as_float(pooled[((long)col << 7) + o8 + q*2 + 1]);
        } else {
          v0 = feat0[br * 128 + o8 + q*2];
          v1 = feat0[br * 128 + o8 + q*2 + 1];
        }
        wq[q] = cvtpk(v0, v1);
      }
#pragma unroll
      for (int q = 0; q < 4; ++q)
        *(unsigned int*)&Bs[j * KWP + 2 + o8 + q*2] = wq[q];   // u32-aligned
    }
    if (tid < NT * 32) {
      int j = tid >> 1, o = tid & 1;
      Bs[j * KWP + o] = f2bf(noderot[(br * 2 + o) * 64 + ((p0 + j) & 63)]);
    }
  }
  if constexpr (INSTR > 0) {
    constexpr int NG = INSTR / 8;
    for (int i = tid; i < NT * 16 * NG; i += 256) {
      int j = i / NG, g = i - j * NG;
      union { bf16x8 v; unsigned int u[4]; } t;
      t.v = *(const bf16x8*)&Bg[(long)(p0 + j) * INSTR + g * 8];
      if constexpr ((HOFF % 8) == 0) {
        *(bf16x8*)&Bs[j * KWP + HOFF + g * 8] = t.v;
      } else {
#pragma unroll
        for (int q = 0; q < 4; ++q)
          *(unsigned int*)&Bs[j * KWP + HOFF + g * 8 + q*2] = t.u[q];
      }
    }
  }
  __syncthreads();
  // ---- MFMA: wave = 16 outs x NT*16 cols ----
  int o0 = blockIdx.y * 64 + wv * 16;
  f32x4 acc[NT];
#pragma unroll
  for (int nt = 0; nt < NT; ++nt)
    acc[nt] = (f32x4){bias[o0 + quad*4], bias[o0 + quad*4 + 1],
                      bias[o0 + quad*4 + 2], bias[o0 + quad*4 + 3]};
  const unsigned short* arow = W + (long)(o0 + lr) * KW;
  for (int ks = 0; ks < KMAIN; ks += 32) {
    bf16x8 a;
    if constexpr ((KW % 8) == 0) {
      a = *(const bf16x8*)(arow + ks + quad*8);
    } else {
      union { bf16x8 v; unsigned int u[4]; } au;
      const unsigned int* ap = (const unsigned int*)(arow + ks + quad*8);  // 4B aligned
      au.u[0] = ap[0]; au.u[1] = ap[1]; au.u[2] = ap[2]; au.u[3] = ap[3];
      a = au.v;
    }
#pragma unroll
    for (int nt = 0; nt < NT; ++nt) {
      bf16x8 bf = *(bf16x8*)&Bs[(nt*16 + lr) * KWP + ks + quad*8];
      acc[nt] = __builtin_amdgcn_mfma_f32_16x16x32_bf16(a, bf, acc[nt], 0, 0, 0);
    }
  }
  if constexpr (REM2) {
#pragma unroll
    for (int rr = 0; rr < 4; ++rr) {
      int o = o0 + quad*4 + rr;
      unsigned int wu = *(const unsigned int*)(W + (long)o * KW + KMAIN);
      float w0 = bf2f(wu & 0xffff), w1 = bf2f(wu >> 16);
#pragma unroll
      for (int nt = 0; nt < NT; ++nt) {
        unsigned int bu = *(unsigned int*)&Bs[(nt*16 + lr) * KWP + KMAIN];
        acc[nt][rr] += w0 * bf2f(bu & 0xffff) + w1 * bf2f(bu >> 16);
      }
    }
  }
  if constexpr (EPI == 0) {
#pragma unroll
    for (int nt = 0; nt < NT; ++nt) {
      unsigned int lo = cvtpk(fmaxf(acc[nt][0], 0.f), fmaxf(acc[nt][1], 0.f));
      unsigned int hi = cvtpk(fmaxf(acc[nt][2], 0.f), fmaxf(acc[nt][3], 0.f));
      unsigned short* op = Out + (long)(p0 + nt*16 + lr) * OSTR + o0 + quad*4;
      *(unsigned long long*)op = (unsigned long long)lo | ((unsigned long long)hi << 32);
    }
  } else {
#pragma unroll
    for (int rr = 0; rr < 4; ++rr) {
      float v = acc[0][rr];
#pragma unroll
      for (int nt = 1; nt < NT; ++nt) v = fmaxf(v, acc[nt][rr]);
      v = fmaxf(v, 0.f);
      v = fmaxf(v, __shfl_xor(v, 1, 64));
      v = fmaxf(v, __shfl_xor(v, 2, 64));
      v = fmaxf(v, __shfl_xor(v, 4, 64));
      v = fmaxf(v, __shfl_xor(v, 8, 64));
      if (lr == 0)
        atomicMax(&outmax[b * FF + o0 + quad*4 + rr], __float_as_uint(v));
    }
    // ---- last-block ticket: convert outmax -> out ----
    __threadfence();
    if (tid == 0) lastf = (atomicAdd(tick, 1) == NBLK - 1) ? 1 : 0;
    __syncthreads();
    if (lastf) {
      int isbf = flag[0];
      for (int t = tid; t < 2048; t += 256) {
        unsigned int u = atomicMax(&outmax[t], 0u);   // device-coherent read
        float v = __uint_as_float(u);
        if (isbf) ((unsigned short*)out)[t] = f2bf(v);
        else      ((float*)out)[t] = v;
      }
    }
  }
}

// ---------------- host ----------------
extern "C" void kernel_launch(void* const* d_in, const int* in_sizes, int n_in,
                              void* d_out, int out_size, void* d_ws, size_t ws_size,
                              hipStream_t stream) {
  const void* x    = d_in[0];
  const void* node = d_in[2];

  // workspace layout (zeroed region first)
  char* ws = (char*)d_ws;
  int*            flag    = (int*)(ws + 0);              //    256 (4 used; tick @ +128)
  int*            tick    = (int*)(ws + 128);            //      4 (zeroed each launch)
  float*          csum    = (float*)(ws + 256);          //   3072
  unsigned int*   outmax  = (unsigned int*)(ws + 3328);  //   8192
  unsigned int*   pooled  = (unsigned int*)(ws + 11520); // 524288
  // ---- end of memset region (535808 B) ----
  int*            idx     = (int*)(ws + 535808);         // 196608
  int*            blkcnt  = (int*)(ws + 732416);         //  16384
  float*          noderot = (float*)(ws + 766208);       //   8192
  int*            rowflag = (int*)(ws + 774400);         //   1024
  int*            sorted  = (int*)(ws + 775424);         // 196608
  float*          feat0   = (float*)(ws + 972032);       //   8192
  unsigned short* fW3p    = (unsigned short*)(ws + 980224);   // 40960 (128x160 bf16)
  float*          Fb      = (float*)(ws + 1021184);      //   8192 (2048 f32)
  unsigned short* Hg3     = (unsigned short*)(ws + 1048576);  // 1048576 (1024x512 bf16)
  unsigned short* Hg1     = (unsigned short*)(ws + 2307328);  // 524288 (1024x256)
  unsigned short* Hg2     = (unsigned short*)(ws + 2831616);  // 524288 (1024x256)
  unsigned short* Wb      = (unsigned short*)(ws + 3355904);  // 1175040

  hipMemsetAsync(ws, 0, 535808, stream);

  WPtrs wp;
  wp.p[0]=d_in[6];  wp.p[1]=d_in[8];  wp.p[2]=d_in[10];             // fpW1,fpW2,fpW3
  wp.p[3]=d_in[12]; wp.p[4]=d_in[14]; wp.p[5]=d_in[16]; wp.p[6]=d_in[18]; // gpW0..3
  wp.p[7]=d_in[4];                                                   // fpW0
  wp.p[8]=d_in[5];  wp.p[9]=d_in[7];  wp.p[10]=d_in[9]; wp.p[11]=d_in[11]; // fpb0..3
  wp.p[12]=d_in[13]; wp.p[13]=d_in[15]; wp.p[14]=d_in[17]; wp.p[15]=d_in[19]; // gpb0..3

  const unsigned short* gW0 = Wb + 28928;   // 256 x 130
  const unsigned short* gW1 = Wb + 62208;   // 256 x 256
  const unsigned short* gW2 = Wb + 127744;  // 512 x 256
  const unsigned short* gW3 = Wb + 258816;  // 512 x 642

  // merged detect + cvt(x8) + assign: blocks [0,298) cvt, [298,362) assign
  k_front<<<362, 256, 0, stream>>>(x, node, wp, flag, Wb, fW3p, Fb, idx, csum, blkcnt);
  // merged means + scatter
  k_scatter2<<<64, 256, 0, stream>>>(csum, blkcnt, idx, sorted, noderot, rowflag);
  // fp block: two 64-col groups per block, 512 threads
  k_fused<<<dim3(96, 16), 512, 0, stream>>>(x, sorted, idx, noderot, flag,
                                            Wb, fW3p, Fb, pooled, feat0);
  // gp chain: 4 per-layer GEMMs, 256-block grids, LDS B-panels
  k_gemm<130, 136, 128, true,  true,  0,   0,   1, 0, 0>
      <<<dim3(64, 4), 256, 0, stream>>>(gW0, Fb + 512, pooled, feat0, rowflag,
                                        noderot, nullptr, Hg1, 256, nullptr,
                                        flag, tick, nullptr);
  k_gemm<256, 264, 256, false, false, 256, 0,   1, 0, 0>
      <<<dim3(64, 4), 256, 0, stream>>>(gW1, Fb + 768, pooled, feat0, rowflag,
                                        noderot, Hg1, Hg2, 256, nullptr,
                                        flag, tick, nullptr);
  k_gemm<256, 264, 256, false, false, 256, 0,   2, 0, 0>
      <<<dim3(32, 8), 256, 0, stream>>>(gW2, Fb + 1024, pooled, feat0, rowflag,
                                        noderot, Hg2, Hg3, 512, nullptr,
                                        flag, tick, nullptr);
  k_gemm<642, 648, 640, true,  true,  512, 130, 2, 2, 256>
      <<<dim3(32, 8), 256, 0, stream>>>(gW3, Fb + 1536, pooled, feat0, rowflag,
                                        noderot, Hg3, nullptr, 0, outmax,
                                        flag, tick, d_out);
}